// Round 2
// baseline (395.170 us; speedup 1.0000x reference)
//
#include <hip/hip_runtime.h>
#include <cstdint>

typedef __bf16 bf16_t;
typedef __attribute__((ext_vector_type(8))) __bf16 bf16x8;
typedef __attribute__((ext_vector_type(4))) __bf16 bf16x4;
typedef __attribute__((ext_vector_type(4))) float f32x4;

#define AS1 __attribute__((address_space(1)))
#define AS3 __attribute__((address_space(3)))

// ---------------------------------------------------------------------------
// Generic NT bf16 GEMM: C[m,n] = sum_k A[m*lda+k] * B[n*ldb+k]
// Tile 128x128, BK=64, 256 threads (4 waves, each wave 64x64 = 4x4 MFMA tiles).
// LDS layout is k-chunk-major: 16B chunk (row, q) lives at chunk index
// q*128 + row  (q = k/8). This makes the 16 lanes of an MFMA quad read 16
// CONSECUTIVE 16B chunks -> 2-way bank aliasing only (free), vs 8-way with
// row-major. Staging achieves this layout by permuting per-lane global
// source addresses (global_load_lds lane->LDS mapping is fixed: base+lane*16).
// causalSkip: skip whole block if n-tile > m-tile (upper triangle).
// kLimit:     Keff = min(K, (bm+1)*128)  (PV causal truncation) + bm flipped
//             so heavy tiles dispatch first.
// ---------------------------------------------------------------------------
template <typename OutT>
__global__ __launch_bounds__(256)
void gemm_nt(const bf16_t* __restrict__ A, const bf16_t* __restrict__ B,
             OutT* __restrict__ C, int K, int lda, int ldb, int ldc,
             long sA, long sB, long sC, int causalSkip, int kLimit)
{
  int bm = blockIdx.y;
  const int bn = blockIdx.x;
  if (kLimit) bm = gridDim.y - 1 - bm;   // heavy (large-Keff) tiles first
  if (causalSkip && bn > bm) return;
  A += (long)blockIdx.z * sA;
  B += (long)blockIdx.z * sB;
  C += (long)blockIdx.z * sC;
  const int m0 = bm * 128, n0 = bn * 128;
  int Keff = K;
  if (kLimit) { const int kl = (bm + 1) * 128; if (kl < Keff) Keff = kl; }

  __shared__ bf16_t As[128 * 64];  // 16KB, chunk index = q*128 + row
  __shared__ bf16_t Bs[128 * 64];  // 16KB

  const int tid = threadIdx.x;
  const int wave = tid >> 6, lane = tid & 63;
  const int lm = lane & 15, qd = lane >> 4;
  const int wm = (wave >> 1) * 64, wn = (wave & 1) * 64;

  // Staging: 1024 chunks per tile; load i of wave w, lane l fills LDS chunk
  // i*256 + w*64 + l. Want that chunk = (row = rl&127, q = i*2 + (rl>>7))
  // where rl = w*64+l. So global source = base(row,hi) + i*16 elements.
  const int rl = wave * 64 + lane;
  const int srow = rl & 127, shi = rl >> 7;
  const bf16_t* Abase = A + (long)(m0 + srow) * lda + shi * 8;
  const bf16_t* Bbase = B + (long)(n0 + srow) * ldb + shi * 8;
  bf16_t* AsW = As + wave * 512;   // wave-uniform LDS bases (chunk w*64)
  bf16_t* BsW = Bs + wave * 512;

  f32x4 acc[4][4] = {};

  for (int k0 = 0; k0 < Keff; k0 += 64) {
#pragma unroll
    for (int i = 0; i < 4; i++) {
      __builtin_amdgcn_global_load_lds((const AS1 void*)(Abase + k0 + i * 16),
                                       (AS3 void*)(AsW + i * 2048), 16, 0, 0);
      __builtin_amdgcn_global_load_lds((const AS1 void*)(Bbase + k0 + i * 16),
                                       (AS3 void*)(BsW + i * 2048), 16, 0, 0);
    }
    __syncthreads();
#pragma unroll
    for (int s = 0; s < 2; s++) {
      bf16x8 aF[4], bF[4];
#pragma unroll
      for (int i = 0; i < 4; i++)
        aF[i] = *(const bf16x8*)&As[(s * 4 + qd) * 1024 + (wm + i * 16 + lm) * 8];
#pragma unroll
      for (int j = 0; j < 4; j++)
        bF[j] = *(const bf16x8*)&Bs[(s * 4 + qd) * 1024 + (wn + j * 16 + lm) * 8];
#pragma unroll
      for (int i = 0; i < 4; i++)
#pragma unroll
        for (int j = 0; j < 4; j++)
          acc[i][j] = __builtin_amdgcn_mfma_f32_16x16x32_bf16(aF[i], bF[j], acc[i][j], 0, 0, 0);
    }
    __syncthreads();
  }

#pragma unroll
  for (int i = 0; i < 4; i++) {
    const int row = m0 + wm + i * 16 + qd * 4;
#pragma unroll
    for (int j = 0; j < 4; j++) {
      const int col = n0 + wn + j * 16 + lm;
#pragma unroll
      for (int r = 0; r < 4; r++)
        C[(long)(row + r) * ldc + col] = (OutT)acc[i][j][r];
    }
  }
}

// ---------------------------------------------------------------------------
// fp32 -> bf16 elementwise (float4 in, bf16x4 out)
// ---------------------------------------------------------------------------
__global__ void cvt_f32_bf16(const float* __restrict__ in, bf16_t* __restrict__ out, int n4)
{
  const int i = blockIdx.x * blockDim.x + threadIdx.x;
  if (i >= n4) return;
  const float4 f = ((const float4*)in)[i];
  bf16x4 o = {(bf16_t)f.x, (bf16_t)f.y, (bf16_t)f.z, (bf16_t)f.w};
  ((bf16x4*)out)[i] = o;
}

// ---------------------------------------------------------------------------
// W [in=1024][out=1024] fp32  ->  WT [out][in] bf16, for z in {q,k,v}
// ---------------------------------------------------------------------------
__global__ void cvt_transpose_w(const float* __restrict__ wq, const float* __restrict__ wk,
                                const float* __restrict__ wv, bf16_t* __restrict__ WT)
{
  const float* W = (blockIdx.z == 0) ? wq : (blockIdx.z == 1) ? wk : wv;
  bf16_t* O = WT + (long)blockIdx.z * 1024 * 1024;
  __shared__ float tile[32][33];
  const int x = blockIdx.x * 32 + threadIdx.x;  // out dim (coalesced read)
  const int y = blockIdx.y * 32 + threadIdx.y;  // in dim
  tile[threadIdx.y][threadIdx.x] = W[(long)y * 1024 + x];
  __syncthreads();
  const int ox = blockIdx.x * 32 + threadIdx.y;  // out row
  const int oy = blockIdx.y * 32 + threadIdx.x;  // in col (coalesced write)
  O[(long)ox * 1024 + oy] = (bf16_t)tile[threadIdx.x][threadIdx.y];
}

// ---------------------------------------------------------------------------
// In-place causal softmax over S rows (bf16, ld=2048). One block per row.
// logits = S/32; writes P = softmax, zeros above the diagonal.
// ---------------------------------------------------------------------------
__global__ __launch_bounds__(256)
void softmax_causal(bf16_t* __restrict__ S)
{
  const int row = blockIdx.x;
  const int t = row & 2047;
  bf16_t* Sr = S + (long)row * 2048;
  const int base = threadIdx.x * 8;

  uint4 u = *(const uint4*)(Sr + base);
  const unsigned short* up = (const unsigned short*)&u;
  float v[8];
  float m = -3.0e38f;
#pragma unroll
  for (int j = 0; j < 8; j++) {
    const float x = __uint_as_float(((unsigned)up[j]) << 16);  // bf16 bits -> f32
    v[j] = (base + j <= t) ? x : -3.0e38f;
    m = fmaxf(m, v[j]);
  }
#pragma unroll
  for (int off = 32; off > 0; off >>= 1) m = fmaxf(m, __shfl_xor(m, off));
  __shared__ float redm[4], redl[4];
  const int wave = threadIdx.x >> 6, lane = threadIdx.x & 63;
  if (lane == 0) redm[wave] = m;
  __syncthreads();
  m = fmaxf(fmaxf(redm[0], redm[1]), fmaxf(redm[2], redm[3]));

  float p[8], l = 0.f;
#pragma unroll
  for (int j = 0; j < 8; j++) {
    p[j] = (base + j <= t) ? __expf((v[j] - m) * 0.03125f) : 0.f;
    l += p[j];
  }
#pragma unroll
  for (int off = 32; off > 0; off >>= 1) l += __shfl_xor(l, off);
  if (lane == 0) redl[wave] = l;
  __syncthreads();
  l = (redl[0] + redl[1]) + (redl[2] + redl[3]);
  const float rl = 1.0f / l;

  uint4 w;
  unsigned* wp = (unsigned*)&w;
#pragma unroll
  for (int h = 0; h < 4; h++) {
    bf16_t a = (bf16_t)(p[2 * h] * rl);
    bf16_t b = (bf16_t)(p[2 * h + 1] * rl);
    wp[h] = (unsigned)__builtin_bit_cast(unsigned short, a) |
            ((unsigned)__builtin_bit_cast(unsigned short, b) << 16);
  }
  *(uint4*)(Sr + base) = w;
}

// ---------------------------------------------------------------------------
extern "C" void kernel_launch(void* const* d_in, const int* in_sizes, int n_in,
                              void* d_out, int out_size, void* d_ws, size_t ws_size,
                              hipStream_t stream)
{
  const float* X  = (const float*)d_in[0];  // [4,2048,1024]
  const float* Wq = (const float*)d_in[1];  // [1024,1024] (in,out)
  const float* Wk = (const float*)d_in[2];
  const float* Wv = (const float*)d_in[3];
  float* out = (float*)d_out;               // [4,2048,1024]

  // workspace layout (bytes): QK 33.5M | VT 16.8M | WT 6.3M | {Xb 16.8M / S 33.5M overlap}
  char* p = (char*)d_ws;
  bf16_t* QK = (bf16_t*)p;  p += (size_t)8192 * 2048 * 2;   // [8192, 2048]  Q|K
  bf16_t* VT = (bf16_t*)p;  p += (size_t)1024 * 8192 * 2;   // [1024, 8192]  V^T
  bf16_t* WT = (bf16_t*)p;  p += (size_t)3072 * 1024 * 2;   // [3072, 1024]  Wq^T|Wk^T|Wv^T
  bf16_t* Xb = (bf16_t*)p;                                  // [8192, 1024]  (dead before S)
  bf16_t* S  = (bf16_t*)p;                                  // [4][2048,2048] scores->P

  // 1) X -> bf16
  cvt_f32_bf16<<<8192, 256, 0, stream>>>(X, Xb, 8388608 / 4);
  // 2) W -> WT (bf16, transposed)
  cvt_transpose_w<<<dim3(32, 32, 3), dim3(32, 32), 0, stream>>>(Wq, Wk, Wv, WT);
  // 3) QK = Xb @ [Wq|Wk]   M=8192 N=2048 K=1024
  gemm_nt<bf16_t><<<dim3(16, 64), 256, 0, stream>>>(
      Xb, WT, QK, 1024, 1024, 1024, 2048, 0, 0, 0, 0, 0);
  // 4) VT = WvT @ Xb^T     M=1024 N=8192 K=1024   (V^T directly, coalesced)
  gemm_nt<bf16_t><<<dim3(64, 8), 256, 0, stream>>>(
      WT + (long)2048 * 1024, Xb, VT, 1024, 1024, 1024, 8192, 0, 0, 0, 0, 0);
  // 5) S = Q @ K^T per batch, lower-triangle tiles only
  gemm_nt<bf16_t><<<dim3(16, 16, 4), 256, 0, stream>>>(
      QK, QK + 1024, S, 1024, 2048, 2048, 2048,
      (long)2048 * 2048, (long)2048 * 2048, (long)2048 * 2048, 1, 0);
  // 6) in-place causal softmax (writes zeros above diagonal)
  softmax_causal<<<8192, 256, 0, stream>>>(S);
  // 7) O = P @ V  (NT vs V^T), K truncated at the diagonal
  gemm_nt<float><<<dim3(8, 16, 4), 256, 0, stream>>>(
      S, VT, out, 2048, 2048, 8192, 1024,
      (long)2048 * 2048, 2048, (long)2048 * 1024, 0, 1);
}

// Round 3
// 264.880 us; speedup vs baseline: 1.4919x; 1.4919x over previous
//
#include <hip/hip_runtime.h>
#include <cstdint>

typedef __bf16 bf16_t;
typedef __attribute__((ext_vector_type(8))) __bf16 bf16x8;
typedef __attribute__((ext_vector_type(4))) __bf16 bf16x4;
typedef __attribute__((ext_vector_type(4))) float f32x4;

#define AS1 __attribute__((address_space(1)))
#define AS3 __attribute__((address_space(3)))

// ---------------------------------------------------------------------------
// Generic NT bf16 GEMM: C[m,n] = sum_k A[m*lda+k] * B[n*ldb+k]
// Tile 128x128, BK=64, 256 threads (4 waves, each wave 64x64 = 4x4 MFMA tiles).
//
// LDS layout: row-major rows of 8 16B-chunks, but chunk q of row r is stored
// at slot q ^ (r&7)  (XOR swizzle). Staging keeps per-row-contiguous global
// reads (8 lanes cover one row's 128B, permuted within the segment — full
// coalescing) while fragment ds_read_b128s spread uniformly over all 32
// banks (8 lanes per 4-bank group = the 8-cycle wave64 minimum, no extra
// conflict cycles). global_load_lds LDS dest stays base+lane*16; the
// permutation lives entirely on the global-source side.
//
// causalSkip: skip whole block if n-tile > m-tile (upper triangle).
// kLimit:     Keff = min(K, (bm+1)*128) (PV causal truncation) + bm flipped
//             so heavy tiles dispatch first.
// ---------------------------------------------------------------------------
template <typename OutT>
__global__ __launch_bounds__(256)
void gemm_nt(const bf16_t* __restrict__ A, const bf16_t* __restrict__ B,
             OutT* __restrict__ C, int K, int lda, int ldb, int ldc,
             long sA, long sB, long sC, int causalSkip, int kLimit)
{
  int bm = blockIdx.y;
  const int bn = blockIdx.x;
  if (kLimit) bm = gridDim.y - 1 - bm;   // heavy (large-Keff) tiles first
  if (causalSkip && bn > bm) return;
  A += (long)blockIdx.z * sA;
  B += (long)blockIdx.z * sB;
  C += (long)blockIdx.z * sC;
  const int m0 = bm * 128, n0 = bn * 128;
  int Keff = K;
  if (kLimit) { const int kl = (bm + 1) * 128; if (kl < Keff) Keff = kl; }

  __shared__ bf16_t As[128 * 64];  // 16KB; elem off = row*64 + (q^(row&7))*8
  __shared__ bf16_t Bs[128 * 64];  // 16KB

  const int tid = threadIdx.x;
  const int wave = tid >> 6, lane = tid & 63;
  const int lm = lane & 15, qd = lane >> 4;
  const int wm = (wave >> 1) * 64, wn = (wave & 1) * 64;

  // Staging: 1024 chunks/tile = 4 loads x 4 waves x 64 lanes.
  // Load i, wave w, lane l -> LDS chunk c = i*256 + w*64 + l.
  // That chunk holds (row = c>>3, q = (c&7) ^ (row&7)).
  // row = i*32 + w*8 + (l>>3); row&7 = l>>3; q = (l&7) ^ (l>>3).
  const int rowl = lane >> 3;           // 0..7
  const int q = (lane & 7) ^ rowl;      // swizzled chunk within row
  const bf16_t* Abase = A + (long)(m0 + wave * 8 + rowl) * lda + q * 8;
  const bf16_t* Bbase = B + (long)(n0 + wave * 8 + rowl) * ldb + q * 8;
  bf16_t* AsW = As + wave * 512;        // wave-uniform LDS bases
  bf16_t* BsW = Bs + wave * 512;

  f32x4 acc[4][4] = {};

  for (int k0 = 0; k0 < Keff; k0 += 64) {
#pragma unroll
    for (int i = 0; i < 4; i++) {
      __builtin_amdgcn_global_load_lds((const AS1 void*)(Abase + (long)i * 32 * lda + k0),
                                       (AS3 void*)(AsW + i * 2048), 16, 0, 0);
      __builtin_amdgcn_global_load_lds((const AS1 void*)(Bbase + (long)i * 32 * ldb + k0),
                                       (AS3 void*)(BsW + i * 2048), 16, 0, 0);
    }
    __syncthreads();
#pragma unroll
    for (int s = 0; s < 2; s++) {
      bf16x8 aF[4], bF[4];
#pragma unroll
      for (int i = 0; i < 4; i++) {
        const int r = wm + i * 16 + lm;
        aF[i] = *(const bf16x8*)&As[r * 64 + (((s * 4 + qd) ^ (lm & 7)) << 3)];
      }
#pragma unroll
      for (int j = 0; j < 4; j++) {
        const int r = wn + j * 16 + lm;
        bF[j] = *(const bf16x8*)&Bs[r * 64 + (((s * 4 + qd) ^ (lm & 7)) << 3)];
      }
#pragma unroll
      for (int i = 0; i < 4; i++)
#pragma unroll
        for (int j = 0; j < 4; j++)
          acc[i][j] = __builtin_amdgcn_mfma_f32_16x16x32_bf16(aF[i], bF[j], acc[i][j], 0, 0, 0);
    }
    __syncthreads();
  }

#pragma unroll
  for (int i = 0; i < 4; i++) {
    const int row = m0 + wm + i * 16 + qd * 4;
#pragma unroll
    for (int j = 0; j < 4; j++) {
      const int col = n0 + wn + j * 16 + lm;
#pragma unroll
      for (int r = 0; r < 4; r++)
        C[(long)(row + r) * ldc + col] = (OutT)acc[i][j][r];
    }
  }
}

// ---------------------------------------------------------------------------
// fp32 -> bf16 elementwise (float4 in, bf16x4 out)
// ---------------------------------------------------------------------------
__global__ void cvt_f32_bf16(const float* __restrict__ in, bf16_t* __restrict__ out, int n4)
{
  const int i = blockIdx.x * blockDim.x + threadIdx.x;
  if (i >= n4) return;
  const float4 f = ((const float4*)in)[i];
  bf16x4 o = {(bf16_t)f.x, (bf16_t)f.y, (bf16_t)f.z, (bf16_t)f.w};
  ((bf16x4*)out)[i] = o;
}

// ---------------------------------------------------------------------------
// W [in=1024][out=1024] fp32  ->  WT [out][in] bf16, for z in {q,k,v}
// ---------------------------------------------------------------------------
__global__ void cvt_transpose_w(const float* __restrict__ wq, const float* __restrict__ wk,
                                const float* __restrict__ wv, bf16_t* __restrict__ WT)
{
  const float* W = (blockIdx.z == 0) ? wq : (blockIdx.z == 1) ? wk : wv;
  bf16_t* O = WT + (long)blockIdx.z * 1024 * 1024;
  __shared__ float tile[32][33];
  const int x = blockIdx.x * 32 + threadIdx.x;  // out dim (coalesced read)
  const int y = blockIdx.y * 32 + threadIdx.y;  // in dim
  tile[threadIdx.y][threadIdx.x] = W[(long)y * 1024 + x];
  __syncthreads();
  const int ox = blockIdx.x * 32 + threadIdx.y;  // out row
  const int oy = blockIdx.y * 32 + threadIdx.x;  // in col (coalesced write)
  O[(long)ox * 1024 + oy] = (bf16_t)tile[threadIdx.x][threadIdx.y];
}

// ---------------------------------------------------------------------------
// In-place causal softmax over S rows (bf16, ld=2048). One block per row.
// logits = S/32; writes P = softmax, zeros above the diagonal.
// ---------------------------------------------------------------------------
__global__ __launch_bounds__(256)
void softmax_causal(bf16_t* __restrict__ S)
{
  const int row = blockIdx.x;
  const int t = row & 2047;
  bf16_t* Sr = S + (long)row * 2048;
  const int base = threadIdx.x * 8;

  uint4 u = *(const uint4*)(Sr + base);
  const unsigned short* up = (const unsigned short*)&u;
  float v[8];
  float m = -3.0e38f;
#pragma unroll
  for (int j = 0; j < 8; j++) {
    const float x = __uint_as_float(((unsigned)up[j]) << 16);  // bf16 bits -> f32
    v[j] = (base + j <= t) ? x : -3.0e38f;
    m = fmaxf(m, v[j]);
  }
#pragma unroll
  for (int off = 32; off > 0; off >>= 1) m = fmaxf(m, __shfl_xor(m, off));
  __shared__ float redm[4], redl[4];
  const int wave = threadIdx.x >> 6, lane = threadIdx.x & 63;
  if (lane == 0) redm[wave] = m;
  __syncthreads();
  m = fmaxf(fmaxf(redm[0], redm[1]), fmaxf(redm[2], redm[3]));

  float p[8], l = 0.f;
#pragma unroll
  for (int j = 0; j < 8; j++) {
    p[j] = (base + j <= t) ? __expf((v[j] - m) * 0.03125f) : 0.f;
    l += p[j];
  }
#pragma unroll
  for (int off = 32; off > 0; off >>= 1) l += __shfl_xor(l, off);
  if (lane == 0) redl[wave] = l;
  __syncthreads();
  l = (redl[0] + redl[1]) + (redl[2] + redl[3]);
  const float rl = 1.0f / l;

  uint4 w;
  unsigned* wp = (unsigned*)&w;
#pragma unroll
  for (int h = 0; h < 4; h++) {
    bf16_t a = (bf16_t)(p[2 * h] * rl);
    bf16_t b = (bf16_t)(p[2 * h + 1] * rl);
    wp[h] = (unsigned)__builtin_bit_cast(unsigned short, a) |
            ((unsigned)__builtin_bit_cast(unsigned short, b) << 16);
  }
  *(uint4*)(Sr + base) = w;
}

// ---------------------------------------------------------------------------
extern "C" void kernel_launch(void* const* d_in, const int* in_sizes, int n_in,
                              void* d_out, int out_size, void* d_ws, size_t ws_size,
                              hipStream_t stream)
{
  const float* X  = (const float*)d_in[0];  // [4,2048,1024]
  const float* Wq = (const float*)d_in[1];  // [1024,1024] (in,out)
  const float* Wk = (const float*)d_in[2];
  const float* Wv = (const float*)d_in[3];
  float* out = (float*)d_out;               // [4,2048,1024]

  // workspace layout (bytes): QK 33.5M | VT 16.8M | WT 6.3M | {Xb 16.8M / S 33.5M overlap}
  char* p = (char*)d_ws;
  bf16_t* QK = (bf16_t*)p;  p += (size_t)8192 * 2048 * 2;   // [8192, 2048]  Q|K
  bf16_t* VT = (bf16_t*)p;  p += (size_t)1024 * 8192 * 2;   // [1024, 8192]  V^T
  bf16_t* WT = (bf16_t*)p;  p += (size_t)3072 * 1024 * 2;   // [3072, 1024]  Wq^T|Wk^T|Wv^T
  bf16_t* Xb = (bf16_t*)p;                                  // [8192, 1024]  (dead before S)
  bf16_t* S  = (bf16_t*)p;                                  // [4][2048,2048] scores->P

  // 1) X -> bf16
  cvt_f32_bf16<<<8192, 256, 0, stream>>>(X, Xb, 8388608 / 4);
  // 2) W -> WT (bf16, transposed)
  cvt_transpose_w<<<dim3(32, 32, 3), dim3(32, 32), 0, stream>>>(Wq, Wk, Wv, WT);
  // 3) QK = Xb @ [Wq|Wk]   M=8192 N=2048 K=1024
  gemm_nt<bf16_t><<<dim3(16, 64), 256, 0, stream>>>(
      Xb, WT, QK, 1024, 1024, 1024, 2048, 0, 0, 0, 0, 0);
  // 4) VT = WvT @ Xb^T     M=1024 N=8192 K=1024   (V^T directly, coalesced)
  gemm_nt<bf16_t><<<dim3(64, 8), 256, 0, stream>>>(
      WT + (long)2048 * 1024, Xb, VT, 1024, 1024, 1024, 8192, 0, 0, 0, 0, 0);
  // 5) S = Q @ K^T per batch, lower-triangle tiles only
  gemm_nt<bf16_t><<<dim3(16, 16, 4), 256, 0, stream>>>(
      QK, QK + 1024, S, 1024, 2048, 2048, 2048,
      (long)2048 * 2048, (long)2048 * 2048, (long)2048 * 2048, 1, 0);
  // 6) in-place causal softmax (writes zeros above diagonal)
  softmax_causal<<<8192, 256, 0, stream>>>(S);
  // 7) O = P @ V  (NT vs V^T), K truncated at the diagonal
  gemm_nt<float><<<dim3(8, 16, 4), 256, 0, stream>>>(
      S, VT, out, 2048, 2048, 8192, 1024,
      (long)2048 * 2048, 2048, (long)2048 * 1024, 0, 1);
}

// Round 4
// 253.161 us; speedup vs baseline: 1.5609x; 1.0463x over previous
//
#include <hip/hip_runtime.h>
#include <cstdint>

typedef __bf16 bf16_t;
typedef __attribute__((ext_vector_type(8))) __bf16 bf16x8;
typedef __attribute__((ext_vector_type(4))) __bf16 bf16x4;
typedef __attribute__((ext_vector_type(4))) float f32x4;

#define AS1 __attribute__((address_space(1)))
#define AS3 __attribute__((address_space(3)))

// ---------------------------------------------------------------------------
// Generic NT bf16 GEMM: C[m,n] = sum_k A[m*lda+k] * B[n*ldb+k]
// Tile 128x128, BK=64, 256 threads (4 waves, each wave 64x64 = 4x4 MFMA tiles).
// DOUBLE-BUFFERED LDS (2x32KB = 64KB, 2 blocks/CU): loads for tile k+1 are
// issued right after the single per-iter barrier, giving them the whole
// compute phase (~1000 cyc) in flight before the next barrier's vmcnt(0)
// drain. One __syncthreads per iter covers both hazards (vmcnt+lgkmcnt).
//
// LDS layout: row-major rows of 8 16B-chunks, chunk q of row r stored at
// slot q ^ (r&7) (XOR swizzle): per-row-contiguous global reads (full
// coalescing) + conflict-free ds_read_b128 (verified: SQ_LDS_BANK_CONFLICT=0).
//
// causalSkip: skip whole block if n-tile > m-tile (upper triangle).
// kLimit:     Keff = min(K, (bm+1)*128) (PV causal truncation) + bm flipped
//             so heavy tiles dispatch first.
// ---------------------------------------------------------------------------
template <typename OutT>
__global__ __launch_bounds__(256)
void gemm_nt(const bf16_t* __restrict__ A, const bf16_t* __restrict__ B,
             OutT* __restrict__ C, int K, int lda, int ldb, int ldc,
             long sA, long sB, long sC, int causalSkip, int kLimit)
{
  int bm = blockIdx.y;
  const int bn = blockIdx.x;
  if (kLimit) bm = gridDim.y - 1 - bm;   // heavy (large-Keff) tiles first
  if (causalSkip && bn > bm) return;
  A += (long)blockIdx.z * sA;
  B += (long)blockIdx.z * sB;
  C += (long)blockIdx.z * sC;
  const int m0 = bm * 128, n0 = bn * 128;
  int Keff = K;
  if (kLimit) { const int kl = (bm + 1) * 128; if (kl < Keff) Keff = kl; }

  __shared__ bf16_t As[2][128 * 64];  // 2 x 16KB
  __shared__ bf16_t Bs[2][128 * 64];  // 2 x 16KB  (64KB total)

  const int tid = threadIdx.x;
  const int wave = tid >> 6, lane = tid & 63;
  const int lm = lane & 15, qd = lane >> 4;
  const int wm = (wave >> 1) * 64, wn = (wave & 1) * 64;

  // Staging: load i, wave w, lane l -> LDS chunk c = i*256 + w*64 + l,
  // holding (row = c>>3, q = (c&7) ^ (row&7)).
  const int rowl = lane >> 3;           // 0..7
  const int q = (lane & 7) ^ rowl;      // swizzled chunk within row
  const bf16_t* Abase = A + (long)(m0 + wave * 8 + rowl) * lda + q * 8;
  const bf16_t* Bbase = B + (long)(n0 + wave * 8 + rowl) * ldb + q * 8;
  const int woff = wave * 512;          // wave-uniform LDS chunk base

#define STAGE(K0, BUF)                                                        \
  _Pragma("unroll")                                                           \
  for (int i = 0; i < 4; i++) {                                               \
    __builtin_amdgcn_global_load_lds(                                         \
        (const AS1 void*)(Abase + (long)i * 32 * lda + (K0)),                 \
        (AS3 void*)(As[BUF] + woff + i * 2048), 16, 0, 0);                    \
    __builtin_amdgcn_global_load_lds(                                         \
        (const AS1 void*)(Bbase + (long)i * 32 * ldb + (K0)),                 \
        (AS3 void*)(Bs[BUF] + woff + i * 2048), 16, 0, 0);                    \
  }

  f32x4 acc[4][4] = {};

  STAGE(0, 0);                           // prologue
  int buf = 0;
  for (int k0 = 0; k0 < Keff; k0 += 64) {
    __syncthreads();                     // drains tile-k loads (issued 1 iter ago)
    if (k0 + 64 < Keff) { STAGE(k0 + 64, buf ^ 1); }
#pragma unroll
    for (int s = 0; s < 2; s++) {
      bf16x8 aF[4], bF[4];
#pragma unroll
      for (int i = 0; i < 4; i++) {
        const int r = wm + i * 16 + lm;
        aF[i] = *(const bf16x8*)&As[buf][r * 64 + (((s * 4 + qd) ^ (lm & 7)) << 3)];
      }
#pragma unroll
      for (int j = 0; j < 4; j++) {
        const int r = wn + j * 16 + lm;
        bF[j] = *(const bf16x8*)&Bs[buf][r * 64 + (((s * 4 + qd) ^ (lm & 7)) << 3)];
      }
#pragma unroll
      for (int i = 0; i < 4; i++)
#pragma unroll
        for (int j = 0; j < 4; j++)
          acc[i][j] = __builtin_amdgcn_mfma_f32_16x16x32_bf16(aF[i], bF[j], acc[i][j], 0, 0, 0);
    }
    buf ^= 1;
  }
#undef STAGE

#pragma unroll
  for (int i = 0; i < 4; i++) {
    const int row = m0 + wm + i * 16 + qd * 4;
#pragma unroll
    for (int j = 0; j < 4; j++) {
      const int col = n0 + wn + j * 16 + lm;
#pragma unroll
      for (int r = 0; r < 4; r++)
        C[(long)(row + r) * ldc + col] = (OutT)acc[i][j][r];
    }
  }
}

// ---------------------------------------------------------------------------
// fp32 -> bf16 elementwise (float4 in, bf16x4 out)
// ---------------------------------------------------------------------------
__global__ void cvt_f32_bf16(const float* __restrict__ in, bf16_t* __restrict__ out, int n4)
{
  const int i = blockIdx.x * blockDim.x + threadIdx.x;
  if (i >= n4) return;
  const float4 f = ((const float4*)in)[i];
  bf16x4 o = {(bf16_t)f.x, (bf16_t)f.y, (bf16_t)f.z, (bf16_t)f.w};
  ((bf16x4*)out)[i] = o;
}

// ---------------------------------------------------------------------------
// W [in=1024][out=1024] fp32  ->  WT [out][in] bf16, for z in {q,k,v}
// ---------------------------------------------------------------------------
__global__ void cvt_transpose_w(const float* __restrict__ wq, const float* __restrict__ wk,
                                const float* __restrict__ wv, bf16_t* __restrict__ WT)
{
  const float* W = (blockIdx.z == 0) ? wq : (blockIdx.z == 1) ? wk : wv;
  bf16_t* O = WT + (long)blockIdx.z * 1024 * 1024;
  __shared__ float tile[32][33];
  const int x = blockIdx.x * 32 + threadIdx.x;  // out dim (coalesced read)
  const int y = blockIdx.y * 32 + threadIdx.y;  // in dim
  tile[threadIdx.y][threadIdx.x] = W[(long)y * 1024 + x];
  __syncthreads();
  const int ox = blockIdx.x * 32 + threadIdx.y;  // out row
  const int oy = blockIdx.y * 32 + threadIdx.x;  // in col (coalesced write)
  O[(long)ox * 1024 + oy] = (bf16_t)tile[threadIdx.x][threadIdx.y];
}

// ---------------------------------------------------------------------------
// In-place causal softmax over S rows (bf16, ld=2048). One block per row.
// logits = S/32; writes P = softmax, zeros above the diagonal.
// ---------------------------------------------------------------------------
__global__ __launch_bounds__(256)
void softmax_causal(bf16_t* __restrict__ S)
{
  const int row = blockIdx.x;
  const int t = row & 2047;
  bf16_t* Sr = S + (long)row * 2048;
  const int base = threadIdx.x * 8;

  uint4 u = *(const uint4*)(Sr + base);
  const unsigned short* up = (const unsigned short*)&u;
  float v[8];
  float m = -3.0e38f;
#pragma unroll
  for (int j = 0; j < 8; j++) {
    const float x = __uint_as_float(((unsigned)up[j]) << 16);  // bf16 bits -> f32
    v[j] = (base + j <= t) ? x : -3.0e38f;
    m = fmaxf(m, v[j]);
  }
#pragma unroll
  for (int off = 32; off > 0; off >>= 1) m = fmaxf(m, __shfl_xor(m, off));
  __shared__ float redm[4], redl[4];
  const int wave = threadIdx.x >> 6, lane = threadIdx.x & 63;
  if (lane == 0) redm[wave] = m;
  __syncthreads();
  m = fmaxf(fmaxf(redm[0], redm[1]), fmaxf(redm[2], redm[3]));

  float p[8], l = 0.f;
#pragma unroll
  for (int j = 0; j < 8; j++) {
    p[j] = (base + j <= t) ? __expf((v[j] - m) * 0.03125f) : 0.f;
    l += p[j];
  }
#pragma unroll
  for (int off = 32; off > 0; off >>= 1) l += __shfl_xor(l, off);
  if (lane == 0) redl[wave] = l;
  __syncthreads();
  l = (redl[0] + redl[1]) + (redl[2] + redl[3]);
  const float rl = 1.0f / l;

  uint4 w;
  unsigned* wp = (unsigned*)&w;
#pragma unroll
  for (int h = 0; h < 4; h++) {
    bf16_t a = (bf16_t)(p[2 * h] * rl);
    bf16_t b = (bf16_t)(p[2 * h + 1] * rl);
    wp[h] = (unsigned)__builtin_bit_cast(unsigned short, a) |
            ((unsigned)__builtin_bit_cast(unsigned short, b) << 16);
  }
  *(uint4*)(Sr + base) = w;
}

// ---------------------------------------------------------------------------
extern "C" void kernel_launch(void* const* d_in, const int* in_sizes, int n_in,
                              void* d_out, int out_size, void* d_ws, size_t ws_size,
                              hipStream_t stream)
{
  const float* X  = (const float*)d_in[0];  // [4,2048,1024]
  const float* Wq = (const float*)d_in[1];  // [1024,1024] (in,out)
  const float* Wk = (const float*)d_in[2];
  const float* Wv = (const float*)d_in[3];
  float* out = (float*)d_out;               // [4,2048,1024]

  // workspace layout (bytes): QK 33.5M | VT 16.8M | WT 6.3M | {Xb 16.8M / S 33.5M overlap}
  char* p = (char*)d_ws;
  bf16_t* QK = (bf16_t*)p;  p += (size_t)8192 * 2048 * 2;   // [8192, 2048]  Q|K
  bf16_t* VT = (bf16_t*)p;  p += (size_t)1024 * 8192 * 2;   // [1024, 8192]  V^T
  bf16_t* WT = (bf16_t*)p;  p += (size_t)3072 * 1024 * 2;   // [3072, 1024]  Wq^T|Wk^T|Wv^T
  bf16_t* Xb = (bf16_t*)p;                                  // [8192, 1024]  (dead before S)
  bf16_t* S  = (bf16_t*)p;                                  // [4][2048,2048] scores->P

  // 1) X -> bf16
  cvt_f32_bf16<<<8192, 256, 0, stream>>>(X, Xb, 8388608 / 4);
  // 2) W -> WT (bf16, transposed)
  cvt_transpose_w<<<dim3(32, 32, 3), dim3(32, 32), 0, stream>>>(Wq, Wk, Wv, WT);
  // 3) QK = Xb @ [Wq|Wk]   M=8192 N=2048 K=1024
  gemm_nt<bf16_t><<<dim3(16, 64), 256, 0, stream>>>(
      Xb, WT, QK, 1024, 1024, 1024, 2048, 0, 0, 0, 0, 0);
  // 4) VT = WvT @ Xb^T     M=1024 N=8192 K=1024   (V^T directly, coalesced)
  gemm_nt<bf16_t><<<dim3(64, 8), 256, 0, stream>>>(
      WT + (long)2048 * 1024, Xb, VT, 1024, 1024, 1024, 8192, 0, 0, 0, 0, 0);
  // 5) S = Q @ K^T per batch, lower-triangle tiles only
  gemm_nt<bf16_t><<<dim3(16, 16, 4), 256, 0, stream>>>(
      QK, QK + 1024, S, 1024, 2048, 2048, 2048,
      (long)2048 * 2048, (long)2048 * 2048, (long)2048 * 2048, 1, 0);
  // 6) in-place causal softmax (writes zeros above diagonal)
  softmax_causal<<<8192, 256, 0, stream>>>(S);
  // 7) O = P @ V  (NT vs V^T), K truncated at the diagonal
  gemm_nt<float><<<dim3(8, 16, 4), 256, 0, stream>>>(
      S, VT, out, 2048, 2048, 8192, 1024,
      (long)2048 * 2048, 2048, (long)2048 * 1024, 0, 1);
}